// Round 12
// baseline (107.776 us; speedup 1.0000x reference)
//
#include <hip/hip_runtime.h>

// SinkhornAttention — round 12: QKV GEMM rebuilt as balanced 4-phase/K-tile
// pipeline: tile 256x128, grid 768 (= exactly 3 rounds @ 1 block/CU), BK=64,
// 8 waves (4Mx2N), pure A/B double-buffer, one vmcnt gate + barrier per
// K-tile, per-phase barriers + setprio for wave role-split (T5).
// All math bit-identical to r11 (absmax margin 0.75 / 0.76).
// Math simplification (round 0, verified): sorted_key/value reduce to the
// block-sum of K/V; Wsort/bsort are dead.

constexpr int BB   = 4;
constexpr int LL   = 4096;
constexpr int DD   = 512;
constexpr int HH   = 8;
constexpr int HDIM = 64;
constexpr int BS   = 64;
constexpr int NBLK = 64;
constexpr int MTOT = BB * LL;   // 16384

using f32x4  = __attribute__((ext_vector_type(4))) float;
typedef __attribute__((ext_vector_type(8))) __bf16 bf16x8;

static __device__ __forceinline__ ushort f2bf(float f) {
  uint u = __float_as_uint(f);
  uint r = (u + 0x7fffu + ((u >> 16) & 1u)) >> 16;   // RNE
  return (ushort)r;
}
static __device__ __forceinline__ float bf2f(ushort u) { return __uint_as_float((uint)u << 16); }
static __device__ __forceinline__ float bflo(uint u) { return __uint_as_float(u << 16); }
static __device__ __forceinline__ float bfhi(uint u) { return __uint_as_float(u & 0xffff0000u); }

// attention-tile swizzle (64x64 bf16 tile, row stride 128 B)
static __device__ __forceinline__ int swb(int row, int cb) {
  return (row << 6) + ((cb ^ ((row & 7) << 4)) >> 1);
}

#define GLOBAL_AS(p) ((const __attribute__((address_space(1))) void*)(p))
#define LDS_AS(p)    ((__attribute__((address_space(3))) void*)(p))
#define SB0()        __builtin_amdgcn_sched_barrier(0)

// ---------------- f32 -> bf16 straight cast (4 elems/thread) -----------------
__global__ __launch_bounds__(256) void f32_to_bf16_vec(
    const float* __restrict__ src, ushort* __restrict__ dst)
{
  const int i = blockIdx.x * 256 + threadIdx.x;
  float4 v = reinterpret_cast<const float4*>(src)[i];
  ushort4 o;
  o.x = f2bf(v.x); o.y = f2bf(v.y); o.z = f2bf(v.z); o.w = f2bf(v.w);
  reinterpret_cast<ushort4*>(dst)[i] = o;
}

// ------------- 4x transpose + cast (one launch): f32 [512][512] -> bf16^T ----
__global__ __launch_bounds__(256) void transpose_cast4(
    const float* __restrict__ Wq, const float* __restrict__ Wk,
    const float* __restrict__ Wv, const float* __restrict__ Wo,
    ushort* __restrict__ Wqkv_t, ushort* __restrict__ Wout_t)
{
  __shared__ float tile[32][33];
  const int z  = blockIdx.z;
  const float* src = (z == 0) ? Wq : (z == 1) ? Wk : (z == 2) ? Wv : Wo;
  ushort* dst = (z < 3) ? (Wqkv_t + (size_t)z * 512 * 512) : Wout_t;
  const int tx = threadIdx.x & 31, ty = threadIdx.x >> 5;   // 32 x 8
  const int r0 = blockIdx.y * 32, c0 = blockIdx.x * 32;
  #pragma unroll
  for (int q = 0; q < 4; ++q)
    tile[ty + 8 * q][tx] = src[(size_t)(r0 + ty + 8 * q) * 512 + c0 + tx];
  __syncthreads();
  #pragma unroll
  for (int q = 0; q < 4; ++q)
    dst[(size_t)(c0 + ty + 8 * q) * 512 + r0 + tx] = f2bf(tile[tx][ty + 8 * q]);
}

// =============== QKV GEMM: 4-phase/K-tile, tile 256x128, BK=64 ==============
// C[M,1536] = A[M,512] @ Bt[1536,512]^T + bias; bf16 scatter into Q/K/V.
// 8 waves as 4M x 2N (wave tile 64x64). Double-buffered A (2x32KB) and
// B (2x16KB) = 96 KB LDS, 1 block/CU, grid 768 = 3 balanced rounds.
// Per K-tile: 4 phases {ds_reads + stage-next-tile | barrier | setprio'd
// 8-MFMA cluster}; single vmcnt(0)+barrier gate at tile end (drained loads
// are >=2 phases old). (g ^ row&7) granule swizzle on 128B rows.
__global__ __launch_bounds__(512, 1) void qkv_4phase(
    const ushort* __restrict__ A, const ushort* __restrict__ Bt,
    const float* __restrict__ b0, const float* __restrict__ b1,
    const float* __restrict__ b2,
    ushort* __restrict__ Cq, ushort* __restrict__ Ck, ushort* __restrict__ Cv)
{
  constexpr int K = 512;
  __shared__ __align__(16) ushort sA[2][256 * 64];   // 32 KB each
  __shared__ __align__(16) ushort sB[2][128 * 64];   // 16 KB each

  const int tid  = threadIdx.x;
  const int lane = tid & 63;
  const int w    = tid >> 6;
  const int wr   = w >> 1;            // 0..3  A-quarter (64 rows)
  const int wc   = w & 1;             // 0..1  B-half (64 cols)
  const int lr   = lane & 15;
  const int kq   = lane >> 4;

  // XCD-chunked swizzle: grid 768 (%8==0), nb fastest within a chunk
  const int cpx  = 768 >> 3;
  const int swz  = ((int)blockIdx.x & 7) * cpx + ((int)blockIdx.x >> 3);
  const int nb   = swz % 12;
  const int mb   = swz / 12;
  const int brow = mb * 256;
  const int bcol = nb * 128;

  // stage chunk j of K-tile kt: 512 thr x 16 B = 8 KB. LDS linear; global
  // source granule pre-swizzled (g ^= row&7) for conflict-free b128 reads.
  auto stA = [&](int buf, int kt, int j) {          // j = 0..3 (256 rows)
    const int c = j * 512 + tid;
    const int row = c >> 3, g = c & 7;
    const ushort* src = A + (size_t)(brow + row) * K + kt * 64 + ((g ^ (row & 7)) << 3);
    __builtin_amdgcn_global_load_lds(GLOBAL_AS(src),
        LDS_AS(&sA[buf][(j * 512 + w * 64) * 8]), 16, 0, 0);
  };
  auto stB = [&](int buf, int kt, int j) {          // j = 0..1 (128 rows)
    const int c = j * 512 + tid;
    const int row = c >> 3, g = c & 7;
    const ushort* src = Bt + (size_t)(bcol + row) * K + kt * 64 + ((g ^ (row & 7)) << 3);
    __builtin_amdgcn_global_load_lds(GLOBAL_AS(src),
        LDS_AS(&sB[buf][(j * 512 + w * 64) * 8]), 16, 0, 0);
  };
  auto rdA = [&](int buf, int mf, int ks) -> bf16x8 {
    const int row = wr * 64 + mf * 16 + lr;
    return *reinterpret_cast<const bf16x8*>(
        &sA[buf][(row << 6) + ((((ks << 2) + kq) ^ (row & 7)) << 3)]);
  };
  auto rdB = [&](int buf, int nf, int ks) -> bf16x8 {
    const int row = wc * 64 + nf * 16 + lr;
    return *reinterpret_cast<const bf16x8*>(
        &sB[buf][(row << 6) + ((((ks << 2) + kq) ^ (row & 7)) << 3)]);
  };

  f32x4 acc[4][4];
  #pragma unroll
  for (int mf = 0; mf < 4; ++mf)
    #pragma unroll
    for (int nf = 0; nf < 4; ++nf)
      acc[mf][nf] = (f32x4){0.f, 0.f, 0.f, 0.f};

  // ---- prologue: stage K-tile 0 into buf0
  stA(0, 0, 0); stA(0, 0, 1); stA(0, 0, 2); stA(0, 0, 3);
  stB(0, 0, 0); stB(0, 0, 1);
  asm volatile("s_waitcnt vmcnt(0)" ::: "memory");
  SB0(); __builtin_amdgcn_s_barrier(); SB0();

  #pragma unroll 1
  for (int t = 0; t < 8; ++t) {
    const int buf  = t & 1;
    const int nbuf = buf ^ 1;
    const bool st  = (t + 1) < 8;
    bf16x8 br[4];

    // ---- phase 0: B(ks0) + A(mf0,mf1; ks0); stage next A0,A1,B0
    #pragma unroll
    for (int nf = 0; nf < 4; ++nf) br[nf] = rdB(buf, nf, 0);
    {
      bf16x8 a0 = rdA(buf, 0, 0), a1 = rdA(buf, 1, 0);
      if (st) { stA(nbuf, t + 1, 0); stA(nbuf, t + 1, 1); stB(nbuf, t + 1, 0); }
      SB0(); __builtin_amdgcn_s_barrier(); SB0();
      __builtin_amdgcn_s_setprio(1);
      #pragma unroll
      for (int nf = 0; nf < 4; ++nf) {
        acc[0][nf] = __builtin_amdgcn_mfma_f32_16x16x32_bf16(a0, br[nf], acc[0][nf], 0, 0, 0);
        acc[1][nf] = __builtin_amdgcn_mfma_f32_16x16x32_bf16(a1, br[nf], acc[1][nf], 0, 0, 0);
      }
      __builtin_amdgcn_s_setprio(0);
    }
    // ---- phase 1: A(mf2,mf3; ks0); stage next A2,A3,B1
    {
      bf16x8 a2 = rdA(buf, 2, 0), a3 = rdA(buf, 3, 0);
      if (st) { stA(nbuf, t + 1, 2); stA(nbuf, t + 1, 3); stB(nbuf, t + 1, 1); }
      SB0(); __builtin_amdgcn_s_barrier(); SB0();
      __builtin_amdgcn_s_setprio(1);
      #pragma unroll
      for (int nf = 0; nf < 4; ++nf) {
        acc[2][nf] = __builtin_amdgcn_mfma_f32_16x16x32_bf16(a2, br[nf], acc[2][nf], 0, 0, 0);
        acc[3][nf] = __builtin_amdgcn_mfma_f32_16x16x32_bf16(a3, br[nf], acc[3][nf], 0, 0, 0);
      }
      __builtin_amdgcn_s_setprio(0);
    }
    // ---- phase 2: B(ks1) + A(mf0,mf1; ks1)
    #pragma unroll
    for (int nf = 0; nf < 4; ++nf) br[nf] = rdB(buf, nf, 1);
    {
      bf16x8 a0 = rdA(buf, 0, 1), a1 = rdA(buf, 1, 1);
      SB0(); __builtin_amdgcn_s_barrier(); SB0();
      __builtin_amdgcn_s_setprio(1);
      #pragma unroll
      for (int nf = 0; nf < 4; ++nf) {
        acc[0][nf] = __builtin_amdgcn_mfma_f32_16x16x32_bf16(a0, br[nf], acc[0][nf], 0, 0, 0);
        acc[1][nf] = __builtin_amdgcn_mfma_f32_16x16x32_bf16(a1, br[nf], acc[1][nf], 0, 0, 0);
      }
      __builtin_amdgcn_s_setprio(0);
    }
    // ---- phase 3: A(mf2,mf3; ks1); tile-end gate
    {
      bf16x8 a2 = rdA(buf, 2, 1), a3 = rdA(buf, 3, 1);
      SB0(); __builtin_amdgcn_s_barrier(); SB0();
      __builtin_amdgcn_s_setprio(1);
      #pragma unroll
      for (int nf = 0; nf < 4; ++nf) {
        acc[2][nf] = __builtin_amdgcn_mfma_f32_16x16x32_bf16(a2, br[nf], acc[2][nf], 0, 0, 0);
        acc[3][nf] = __builtin_amdgcn_mfma_f32_16x16x32_bf16(a3, br[nf], acc[3][nf], 0, 0, 0);
      }
      __builtin_amdgcn_s_setprio(0);
      SB0();
      if (st) asm volatile("s_waitcnt vmcnt(0)" ::: "memory");  // loads >=2 phases old
      SB0(); __builtin_amdgcn_s_barrier(); SB0();
    }
  }

  // ---- epilogue: LDS-staged, coalesced 16-B stores (values bit-identical) ---
  ushort* sEp = (ushort*)&sA[0][0];               // 64 x 144 bf16 = 18 KB
  constexpr int ES = 128 + 16;
  const int which = bcol >> 9;                    // tile never straddles 512
  ushort* dst = (which == 0) ? Cq : ((which == 1) ? Ck : Cv);
  const float* bsel = (which == 0) ? b0 : ((which == 1) ? b1 : b2);
  const int ncol0 = bcol & 511;
  #pragma unroll
  for (int mf = 0; mf < 4; ++mf) {
    if (mf) __syncthreads();
    #pragma unroll
    for (int nf = 0; nf < 4; ++nf) {
      const int col = wc * 64 + nf * 16 + lr;
      const float bb = bsel[ncol0 + col];
      #pragma unroll
      for (int r = 0; r < 4; ++r)
        sEp[(wr * 16 + kq * 4 + r) * ES + col] = f2bf(acc[mf][nf][r] + bb);
    }
    __syncthreads();
    #pragma unroll
    for (int it = 0; it < 2; ++it) {
      const int idx = tid + it * 512;             // 1024 16-B chunks
      const int rr  = idx >> 4;                   // 0..63
      const int cc  = (idx & 15) * 8;
      uint4 v = *reinterpret_cast<const uint4*>(&sEp[rr * ES + cc]);
      const int grow = brow + (rr >> 4) * 64 + mf * 16 + (rr & 15);
      *reinterpret_cast<uint4*>(&dst[(size_t)grow * DD + ncol0 + cc]) = v;
    }
  }
}

// ---------------- 2-phase pipelined GEMM (out-projection, f32 out) -----------
__global__ __launch_bounds__(256, 3) void gemm_out(
    const ushort* __restrict__ A, const ushort* __restrict__ Bt,
    const float* __restrict__ bias, float* __restrict__ Cf)
{
  constexpr int K  = 512;
  constexpr int NT = K / 32;
  constexpr int N  = 512;
  __shared__ __align__(16) ushort sA[3][128 * 32];
  __shared__ __align__(16) ushort sB[3][128 * 32];

  const int tid  = threadIdx.x;
  const int lane = tid & 63;
  const int w    = tid >> 6;
  const int wr   = w >> 1, wc = w & 1;
  const int lr   = lane & 15;
  const int kq   = lane >> 4;

  const int cpx  = 512 >> 3;
  const int swz  = ((int)blockIdx.x & 7) * cpx + ((int)blockIdx.x >> 3);
  const int nb   = swz % 4;
  const int mb   = swz / 4;
  const int brow = mb * 128;
  const int bcol = nb * 128;

  auto stageA = [&](int buf, int t, int j) {
    const int c   = j * 256 + tid;
    const int row = c >> 2, ch = c & 3;
    const ushort* src = A + (size_t)(brow + row) * K + t * 32 + ((ch ^ ((row >> 1) & 3)) << 3);
    __builtin_amdgcn_global_load_lds(GLOBAL_AS(src),
        LDS_AS(&sA[buf][(j * 256 + (w << 6)) << 3]), 16, 0, 0);
  };
  auto stageB = [&](int buf, int t, int j) {
    const int c   = j * 256 + tid;
    const int row = c >> 2, ch = c & 3;
    const ushort* src = Bt + (size_t)(bcol + row) * K + t * 32 + ((ch ^ ((row >> 1) & 3)) << 3);
    __builtin_amdgcn_global_load_lds(GLOBAL_AS(src),
        LDS_AS(&sB[buf][(j * 256 + (w << 6)) << 3]), 16, 0, 0);
  };
  auto ldA = [&](int buf, int mf) -> bf16x8 {
    const int row = (wr << 6) + (mf << 4) + lr;
    return *reinterpret_cast<const bf16x8*>(&sA[buf][(row << 5) + ((kq ^ ((row >> 1) & 3)) << 3)]);
  };
  auto ldB = [&](int buf, int nf) -> bf16x8 {
    const int row = (wc << 6) + (nf << 4) + lr;
    return *reinterpret_cast<const bf16x8*>(&sB[buf][(row << 5) + ((kq ^ ((row >> 1) & 3)) << 3)]);
  };

  f32x4 acc[4][4];
  #pragma unroll
  for (int mi = 0; mi < 4; ++mi)
    #pragma unroll
    for (int ni = 0; ni < 4; ++ni)
      acc[mi][ni] = (f32x4){0.f, 0.f, 0.f, 0.f};

  stageA(0, 0, 0); stageA(0, 0, 1); stageB(0, 0, 0); stageB(0, 0, 1);
  stageA(1, 1, 0); stageA(1, 1, 1); stageB(1, 1, 0); stageB(1, 1, 1);
  asm volatile("s_waitcnt vmcnt(4)" ::: "memory");
  SB0(); __builtin_amdgcn_s_barrier(); SB0();

  for (int t = 0; t < NT; ++t) {
    const int buf  = t % 3;
    const int nbuf = (t + 2) % 3;
    const bool more = (t + 2) < NT;

    bf16x8 af[4], bfr[4];
    #pragma unroll
    for (int mf = 0; mf < 4; ++mf) af[mf] = ldA(buf, mf);
    #pragma unroll
    for (int nf = 0; nf < 4; ++nf) bfr[nf] = ldB(buf, nf);
    if (more) { stageA(nbuf, t + 2, 0); stageA(nbuf, t + 2, 1);
                stageB(nbuf, t + 2, 0); stageB(nbuf, t + 2, 1); }
    SB0();
    __builtin_amdgcn_s_setprio(1);
    #pragma unroll
    for (int mi = 0; mi < 4; ++mi)
      #pragma unroll
      for (int ni = 0; ni < 4; ++ni)
        acc[mi][ni] = __builtin_amdgcn_mfma_f32_16x16x32_bf16(af[mi], bfr[ni], acc[mi][ni], 0, 0, 0);
    __builtin_amdgcn_s_setprio(0);
    SB0();
    if (more) asm volatile("s_waitcnt vmcnt(4)" ::: "memory");
    else      asm volatile("s_waitcnt vmcnt(0)" ::: "memory");
    SB0(); __builtin_amdgcn_s_barrier(); SB0();
  }

  float* sEpF = (float*)&sA[0][0];              // 32 x 136 f32
  constexpr int ES = 128 + 8;
  #pragma unroll
  for (int mi = 0; mi < 4; ++mi) {
    if (mi) __syncthreads();
    #pragma unroll
    for (int nf = 0; nf < 4; ++nf) {
      const int col = wc * 64 + nf * 16 + lr;
      const float bb = bias[bcol + col];
      #pragma unroll
      for (int r = 0; r < 4; ++r)
        sEpF[(wr * 16 + kq * 4 + r) * ES + col] = acc[mi][nf][r] + bb;
    }
    __syncthreads();
    #pragma unroll
    for (int it = 0; it < 4; ++it) {
      const int idx = tid + it * 256;
      const int rr  = idx >> 5;
      const int cc  = (idx & 31) * 4;
      float4 v = *reinterpret_cast<const float4*>(&sEpF[rr * ES + cc]);
      const int grow = brow + (rr >> 4) * 64 + mi * 16 + (rr & 15);
      *reinterpret_cast<float4*>(&Cf[(size_t)grow * N + bcol + cc]) = v;
    }
  }
}

// ---------------- fused block-sum of K,V -> Khi/Klo/Vb (no atomics) ----------
__global__ __launch_bounds__(256) void sumkv_fused(
    const ushort* __restrict__ K, const ushort* __restrict__ V,
    ushort* __restrict__ Khi, ushort* __restrict__ Klo, ushort* __restrict__ Vb)
{
  __shared__ float kbuf[4][64][9];
  __shared__ float vbuf[4][64][9];
  const int bs   = blockIdx.x;          // b*64 + s
  const int b    = bs >> 6, s = bs & 63;
  const int lane = threadIdx.x & 63;
  const int kbq  = threadIdx.x >> 6;
  const size_t rowbase = ((size_t)b * LL + s) * DD + lane * 8;

  uint4 ku[16], vu[16];
  #pragma unroll
  for (int i = 0; i < 16; ++i) {
    const size_t off = rowbase + (size_t)(kbq * 16 + i) * BS * DD;
    ku[i] = *reinterpret_cast<const uint4*>(K + off);
    vu[i] = *reinterpret_cast<const uint4*>(V + off);
  }
  float ak[8] = {0,0,0,0,0,0,0,0}, av[8] = {0,0,0,0,0,0,0,0};
  #pragma unroll
  for (int i = 0; i < 16; ++i) {
    ak[0] += bflo(ku[i].x); ak[1] += bfhi(ku[i].x); ak[2] += bflo(ku[i].y); ak[3] += bfhi(ku[i].y);
    ak[4] += bflo(ku[i].z); ak[5] += bfhi(ku[i].z); ak[6] += bflo(ku[i].w); ak[7] += bfhi(ku[i].w);
    av[0] += bflo(vu[i].x); av[1] += bfhi(vu[i].x); av[2] += bflo(vu[i].y); av[3] += bfhi(vu[i].y);
    av[4] += bflo(vu[i].z); av[5] += bfhi(vu[i].z); av[6] += bflo(vu[i].w); av[7] += bfhi(vu[i].w);
  }
  #pragma unroll
  for (int j = 0; j < 8; ++j) { kbuf[kbq][lane][j] = ak[j]; vbuf[kbq][lane][j] = av[j]; }
  __syncthreads();

  const size_t wbase = (size_t)bs * DD + lane * 8;
  if (kbq == 0) {
    uint4 hi4, lo4;
    uint* hp = reinterpret_cast<uint*>(&hi4);
    uint* lp = reinterpret_cast<uint*>(&lo4);
    #pragma unroll
    for (int p = 0; p < 4; ++p) {
      uint hw = 0, lw = 0;
      #pragma unroll
      for (int q = 0; q < 2; ++q) {
        const int j = p * 2 + q;
        const float t = kbuf[0][lane][j] + kbuf[1][lane][j] +
                        kbuf[2][lane][j] + kbuf[3][lane][j];
        const ushort h = f2bf(t);
        const ushort l = f2bf(t - bf2f(h));
        hw |= (uint)h << (16 * q);
        lw |= (uint)l << (16 * q);
      }
      hp[p] = hw; lp[p] = lw;
    }
    *reinterpret_cast<uint4*>(Khi + wbase) = hi4;
    *reinterpret_cast<uint4*>(Klo + wbase) = lo4;
  } else if (kbq == 1) {
    uint4 o4;
    uint* op = reinterpret_cast<uint*>(&o4);
    #pragma unroll
    for (int p = 0; p < 4; ++p) {
      uint wv = 0;
      #pragma unroll
      for (int q = 0; q < 2; ++q) {
        const int j = p * 2 + q;
        const float t = vbuf[0][lane][j] + vbuf[1][lane][j] +
                        vbuf[2][lane][j] + vbuf[3][lane][j];
        wv |= (uint)f2bf(t) << (16 * q);
      }
      op[p] = wv;
    }
    *reinterpret_cast<uint4*>(Vb + wbase) = o4;
  }
}

// ---------------- MFMA two-pass block attention ------------------------------
// 24 KB LDS (sP aliased onto Klo buffer sCP) -> 6 blocks/CU; XCD-chunked grid.
__global__ __launch_bounds__(256) void attn_mfma(
    const ushort* __restrict__ Q, const ushort* __restrict__ Kg,
    const ushort* __restrict__ Vg, const ushort* __restrict__ Khi,
    const ushort* __restrict__ Klo, const ushort* __restrict__ Vsb,
    ushort* __restrict__ X)
{
  __shared__ __align__(16) ushort sA[64 * 64];   // K (pass1), Khi (pass2)
  __shared__ __align__(16) ushort sVt[64 * 64];  // V^T, then Vsum^T
  __shared__ __align__(16) ushort sCP[64 * 64];  // P (both passes) / Klo (pass2)
  const int bid = blockIdx.x;
  const int swz = (bid & 7) * 256 + (bid >> 3);  // XCD-chunked (2048 % 8 == 0)
  const int n = swz & 63, h = (swz >> 6) & 7, b = swz >> 9;
  const int tid  = threadIdx.x;
  const int lane = tid & 63;
  const int w    = tid >> 6;
  const int lr   = lane & 15, hi4 = lane >> 4;
  const float scale = 0.125f;

  const size_t tbase = ((size_t)(b * LL + n * BS)) * DD + h * HDIM;
  const size_t sbase = ((size_t)(b * BS)) * DD + h * HDIM;

  uint4 k1[2], v1[2], k2h[2], k2l[2], v2[2];
  int rr[2], cc[2];
  #pragma unroll
  for (int it = 0; it < 2; ++it) {
    const int i  = tid + it * 256;      // 0..511
    const int r  = i >> 3;
    const int c8 = (i & 7) << 3;
    rr[it] = r; cc[it] = c8;
    const size_t g1 = tbase + (size_t)r * DD + c8;
    const size_t g2 = sbase + (size_t)r * DD + c8;
    k1[it]  = *reinterpret_cast<const uint4*>(Kg  + g1);
    v1[it]  = *reinterpret_cast<const uint4*>(Vg  + g1);
    k2h[it] = *reinterpret_cast<const uint4*>(Khi + g2);
    k2l[it] = *reinterpret_cast<const uint4*>(Klo + g2);
    v2[it]  = *reinterpret_cast<const uint4*>(Vsb + g2);
  }
  bf16x8 qf[2];
  #pragma unroll
  for (int ks = 0; ks < 2; ++ks)
    qf[ks] = *reinterpret_cast<const bf16x8*>(
        Q + tbase + (size_t)(w * 16 + lr) * DD + ks * 32 + hi4 * 8);

  #pragma unroll
  for (int it = 0; it < 2; ++it) {
    *reinterpret_cast<uint4*>(&sA[swb(rr[it], cc[it] << 1)]) = k1[it];
    const uint u[4] = {v1[it].x, v1[it].y, v1[it].z, v1[it].w};
    #pragma unroll
    for (int j = 0; j < 4; ++j) {
      sVt[swb(cc[it] + 2 * j,     rr[it] << 1)] = (ushort)(u[j] & 0xffff);
      sVt[swb(cc[it] + 2 * j + 1, rr[it] << 1)] = (ushort)(u[j] >> 16);
    }
  }
  __syncthreads();

  f32x4 xacc[4];
  #pragma unroll
  for (int dt = 0; dt < 4; ++dt) xacc[dt] = (f32x4){0.f, 0.f, 0.f, 0.f};

  // ================= PASS 1 =================
  {
    f32x4 st[4];
    #pragma unroll
    for (int t = 0; t < 4; ++t) st[t] = (f32x4){0.f, 0.f, 0.f, 0.f};
    #pragma unroll
    for (int ks = 0; ks < 2; ++ks) {
      #pragma unroll
      for (int t = 0; t < 4; ++t) {
        bf16x8 kf = *reinterpret_cast<const bf16x8*>(
            &sA[swb(t * 16 + lr, (ks * 32 + hi4 * 8) << 1)]);
        st[t] = __builtin_amdgcn_mfma_f32_16x16x32_bf16(kf, qf[ks], st[t], 0, 0, 0);
      }
    }
    float e[4][4];
    float mx = -1e30f;
    #pragma unroll
    for (int t = 0; t < 4; ++t)
      #pragma unroll
      for (int r = 0; r < 4; ++r) { e[t][r] = st[t][r] * scale; mx = fmaxf(mx, e[t][r]); }
    mx = fmaxf(mx, __shfl_xor(mx, 16));
    mx = fmaxf(mx, __shfl_xor(mx, 32));
    float sum = 0.f;
    #pragma unroll
    for (int t = 0; t < 4; ++t)
      #pragma unroll
      for (int r = 0; r < 4; ++r) { e[t][r] = __expf(e[t][r] - mx); sum += e[t][r]; }
    sum += __shfl_xor(sum, 16);
    sum += __shfl_xor(sum, 32);
    const float inv = 1.0f / sum;
    #pragma unroll
    for (int t = 0; t < 4; ++t) {
      ushort4 p4;
      p4.x = f2bf(e[t][0] * inv); p4.y = f2bf(e[t][1] * inv);
      p4.z = f2bf(e[t][2] * inv); p4.w = f2bf(e[t][3] * inv);
      *reinterpret_cast<ushort4*>(&sCP[swb(w * 16 + lr, (t * 16 + hi4 * 4) << 1)]) = p4;
    }
    #pragma unroll
    for (int ks = 0; ks < 2; ++ks) {
      bf16x8 pa = *reinterpret_cast<const bf16x8*>(
          &sCP[swb(w * 16 + lr, (ks * 32 + hi4 * 8) << 1)]);
      #pragma unroll
      for (int dt = 0; dt < 4; ++dt) {
        bf16x8 vb = *reinterpret_cast<const bf16x8*>(
            &sVt[swb(dt * 16 + lr, (ks * 32 + hi4 * 8) << 1)]);
        xacc[dt] = __builtin_amdgcn_mfma_f32_16x16x32_bf16(pa, vb, xacc[dt], 0, 0, 0);
      }
    }
  }
  __syncthreads();

  #pragma unroll
  for (int it = 0; it < 2; ++it) {
    *reinterpret_cast<uint4*>(&sA[swb(rr[it], cc[it] << 1)])  = k2h[it];
    *reinterpret_cast<uint4*>(&sCP[swb(rr[it], cc[it] << 1)]) = k2l[it];
    const uint u[4] = {v2[it].x, v2[it].y, v2[it].z, v2[it].w};
    #pragma unroll
    for (int j = 0; j < 4; ++j) {
      sVt[swb(cc[it] + 2 * j,     rr[it] << 1)] = (ushort)(u[j] & 0xffff);
      sVt[swb(cc[it] + 2 * j + 1, rr[it] << 1)] = (ushort)(u[j] >> 16);
    }
  }
  __syncthreads();

  // ================= PASS 2 =================
  {
    f32x4 st[4];
    #pragma unroll
    for (int t = 0; t < 4; ++t) st[t] = (f32x4){0.f, 0.f, 0.f, 0.f};
    #pragma unroll
    for (int ks = 0; ks < 2; ++ks) {
      #pragma unroll
      for (int t = 0; t < 4; ++t) {
        bf16x8 kh = *reinterpret_cast<const bf16x8*>(
            &sA[swb(t * 16 + lr, (ks * 32 + hi4 * 8) << 1)]);
        st[t] = __builtin_amdgcn_mfma_f32_16x16x32_bf16(kh, qf[ks], st[t], 0, 0, 0);
        bf16x8 kl = *reinterpret_cast<const bf16x8*>(
            &sCP[swb(t * 16 + lr, (ks * 32 + hi4 * 8) << 1)]);
        st[t] = __builtin_amdgcn_mfma_f32_16x16x32_bf16(kl, qf[ks], st[t], 0, 0, 0);
      }
    }
    __syncthreads();   // all Klo reads done before P overwrites sCP
    float e[4][4];
    float mx = -1e30f;
    #pragma unroll
    for (int t = 0; t < 4; ++t)
      #pragma unroll
      for (int r = 0; r < 4; ++r) { e[t][r] = st[t][r] * scale; mx = fmaxf(mx, e[t][r]); }
    mx = fmaxf(mx, __shfl_xor(mx, 16));
    mx = fmaxf(mx, __shfl_xor(mx, 32));
    float sum = 0.f;
    #pragma unroll
    for (int t = 0; t < 4; ++t)
      #pragma unroll
      for (int r = 0; r < 4; ++r) { e[t][r] = __expf(e[t][r] - mx); sum += e[t][r]; }
    sum += __shfl_xor(sum, 16);
    sum += __shfl_xor(sum, 32);
    const float inv = 1.0f / sum;
    #pragma unroll
    for (int t = 0; t < 4; ++t) {
      ushort4 p4;
      p4.x = f2bf(e[t][0] * inv); p4.y = f2bf(e[t][1] * inv);
      p4.z = f2bf(e[t][2] * inv); p4.w = f2bf(e[t][3] * inv);
      *reinterpret_cast<ushort4*>(&sCP[swb(w * 16 + lr, (t * 16 + hi4 * 4) << 1)]) = p4;
    }
    #pragma unroll
    for (int ks = 0; ks < 2; ++ks) {
      bf16x8 pa = *reinterpret_cast<const bf16x8*>(
          &sCP[swb(w * 16 + lr, (ks * 32 + hi4 * 8) << 1)]);
      #pragma unroll
      for (int dt = 0; dt < 4; ++dt) {
        bf16x8 vb = *reinterpret_cast<const bf16x8*>(
            &sVt[swb(dt * 16 + lr, (ks * 32 + hi4 * 8) << 1)]);
        xacc[dt] = __builtin_amdgcn_mfma_f32_16x16x32_bf16(pa, vb, xacc[dt], 0, 0, 0);
      }
    }
  }

  #pragma unroll
  for (int dt = 0; dt < 4; ++dt)
    #pragma unroll
    for (int r = 0; r < 4; ++r)
      X[tbase + (size_t)(w * 16 + hi4 * 4 + r) * DD + dt * 16 + lr] = f2bf(xacc[dt][r]);
}

// ---------------- launcher ---------------------------------------------------
extern "C" void kernel_launch(void* const* d_in, const int* in_sizes, int n_in,
                              void* d_out, int out_size, void* d_ws, size_t ws_size,
                              hipStream_t stream) {
  const float* x_in = (const float*)d_in[0];
  const float* Wq   = (const float*)d_in[1];
  const float* bq   = (const float*)d_in[2];
  const float* Wk   = (const float*)d_in[3];
  const float* bk   = (const float*)d_in[4];
  const float* Wv   = (const float*)d_in[5];
  const float* bv   = (const float*)d_in[6];
  const float* Wout = (const float*)d_in[9];
  const float* bout = (const float*)d_in[10];
  float* out = (float*)d_out;

  const size_t NTOK = (size_t)MTOT * DD;          // 8,388,608 elems
  const size_t NSUM = (size_t)BB * BS * DD;       // 131072 elems
  char* ws = (char*)d_ws;
  ushort* xb      = (ushort*)ws;            ws += NTOK * 2;
  ushort* Qb      = (ushort*)ws;            ws += NTOK * 2;
  ushort* Kb      = (ushort*)ws;            ws += NTOK * 2;
  ushort* Vb      = (ushort*)ws;            ws += NTOK * 2;
  ushort* Xb      = (ushort*)ws;            ws += NTOK * 2;
  ushort* Wqkv_t  = (ushort*)ws;            ws += (size_t)1536 * 512 * 2;
  ushort* Wout_t  = (ushort*)ws;            ws += (size_t)512 * 512 * 2;
  ushort* KhiB    = (ushort*)ws;            ws += NSUM * 2;
  ushort* KloB    = (ushort*)ws;            ws += NSUM * 2;
  ushort* VsB     = (ushort*)ws;            ws += NSUM * 2;

  f32_to_bf16_vec<<<NTOK / 4 / 256, 256, 0, stream>>>(x_in, xb);
  transpose_cast4<<<dim3(16, 16, 4), 256, 0, stream>>>(
      Wq, Wk, Wv, Wout, Wqkv_t, Wout_t);

  // QKV: tile 256x128, grid 64*12 = 768 (= 3 balanced rounds @ 1 block/CU)
  qkv_4phase<<<768, 512, 0, stream>>>(
      xb, Wqkv_t, bq, bk, bv, Qb, Kb, Vb);

  sumkv_fused<<<BB * BS, 256, 0, stream>>>(Kb, Vb, KhiB, KloB, VsB);

  attn_mfma<<<BB * HH * NBLK, 256, 0, stream>>>(Qb, Kb, Vb, KhiB, KloB, VsB, Xb);

  // out: tile 128x128, grid 4*128 = 512 (fully resident at 3 blocks/CU)
  gemm_out<<<4 * 128, 256, 0, stream>>>(Xb, Wout_t, bout, out);
}

// Round 13
// 98.288 us; speedup vs baseline: 1.0965x; 1.0965x over previous
//
#include <hip/hip_runtime.h>

// SinkhornAttention — round 13: revert to r11 (best: 99.69 us; r12's 4-phase
// 1-block/CU QKV regressed — no co-resident overlap). Single change: fuse the
// bf16-cast and weight-transpose prep into one launch (range-dispatched).
// All math bit-identical (absmax margin 0.75 / 0.76).
// Math simplification (round 0, verified): sorted_key/value reduce to the
// block-sum of K/V; Wsort/bsort are dead.

constexpr int BB   = 4;
constexpr int LL   = 4096;
constexpr int DD   = 512;
constexpr int HH   = 8;
constexpr int HDIM = 64;
constexpr int BS   = 64;
constexpr int NBLK = 64;
constexpr int MTOT = BB * LL;   // 16384

using f32x4  = __attribute__((ext_vector_type(4))) float;
typedef __attribute__((ext_vector_type(8))) __bf16 bf16x8;

static __device__ __forceinline__ ushort f2bf(float f) {
  uint u = __float_as_uint(f);
  uint r = (u + 0x7fffu + ((u >> 16) & 1u)) >> 16;   // RNE
  return (ushort)r;
}
static __device__ __forceinline__ float bf2f(ushort u) { return __uint_as_float((uint)u << 16); }
static __device__ __forceinline__ float bflo(uint u) { return __uint_as_float(u << 16); }
static __device__ __forceinline__ float bfhi(uint u) { return __uint_as_float(u & 0xffff0000u); }

// attention-tile swizzle (64x64 bf16 tile, row stride 128 B)
static __device__ __forceinline__ int swb(int row, int cb) {
  return (row << 6) + ((cb ^ ((row & 7) << 4)) >> 1);
}

#define GLOBAL_AS(p) ((const __attribute__((address_space(1))) void*)(p))
#define LDS_AS(p)    ((__attribute__((address_space(3))) void*)(p))
#define SB0()        __builtin_amdgcn_sched_barrier(0)

// ------- fused prep: blocks [0,8192) cast x -> bf16; [8192,9216) transpose ---
__global__ __launch_bounds__(256) void prep_fused(
    const float* __restrict__ x_in, ushort* __restrict__ xb,
    const float* __restrict__ Wq, const float* __restrict__ Wk,
    const float* __restrict__ Wv, const float* __restrict__ Wo,
    ushort* __restrict__ Wqkv_t, ushort* __restrict__ Wout_t)
{
  __shared__ float tile[32][33];
  const int bid = blockIdx.x;
  if (bid < 8192) {
    const int i = bid * 256 + threadIdx.x;
    float4 v = reinterpret_cast<const float4*>(x_in)[i];
    ushort4 o;
    o.x = f2bf(v.x); o.y = f2bf(v.y); o.z = f2bf(v.z); o.w = f2bf(v.w);
    reinterpret_cast<ushort4*>(xb)[i] = o;
  } else {
    const int rem = bid - 8192;               // 0..1023
    const int z  = rem >> 8;                  // 0..3
    const float* src = (z == 0) ? Wq : (z == 1) ? Wk : (z == 2) ? Wv : Wo;
    ushort* dst = (z < 3) ? (Wqkv_t + (size_t)z * 512 * 512) : Wout_t;
    const int tx = threadIdx.x & 31, ty = threadIdx.x >> 5;   // 32 x 8
    const int r0 = ((rem >> 4) & 15) * 32, c0 = (rem & 15) * 32;
    #pragma unroll
    for (int q = 0; q < 4; ++q)
      tile[ty + 8 * q][tx] = src[(size_t)(r0 + ty + 8 * q) * 512 + c0 + tx];
    __syncthreads();
    #pragma unroll
    for (int q = 0; q < 4; ++q)
      dst[(size_t)(c0 + ty + 8 * q) * 512 + r0 + tx] = f2bf(tile[tx][ty + 8 * q]);
  }
}

// ---------------- pipelined MFMA GEMM: C[M,N] = A[M,512] @ Bt[N,512]^T + b ---
// Block tile 128x128, BK=32, 4 waves (2x2), 3-deep LDS pipeline (48 KB ->
// 3 blocks/CU), counted vmcnt(4) gates, 1 raw barrier per K-step,
// (row>>1)&3 granule swizzle (2-way = free ds_read_b128).
// MODE 0: bf16 into Q/K/V (tile-uniform tensor+bias select). MODE 1: f32 out.
template<int MODE>
__global__ __launch_bounds__(256, 3) void gemm_pipe3(
    const ushort* __restrict__ A, const ushort* __restrict__ Bt,
    const float* __restrict__ b0, const float* __restrict__ b1,
    const float* __restrict__ b2,
    ushort* __restrict__ Cq, ushort* __restrict__ Ck, ushort* __restrict__ Cv,
    float* __restrict__ Cf, int N, int NBX)
{
  constexpr int K  = 512;
  constexpr int NT = K / 32;          // 16 K-steps
  constexpr int TN = 128;
  __shared__ __align__(16) ushort sA[3][128 * 32];
  __shared__ __align__(16) ushort sB[3][128 * 32];

  const int tid  = threadIdx.x;
  const int lane = tid & 63;
  const int w    = tid >> 6;
  const int wr   = w >> 1, wc = w & 1;
  const int lr   = lane & 15;
  const int kq   = lane >> 4;

  // XCD-chunked block swizzle (grid % 8 == 0), nb fastest within a chunk
  const int nwg  = NBX * 128;
  const int cpx  = nwg >> 3;
  const int swz  = ((int)blockIdx.x & 7) * cpx + ((int)blockIdx.x >> 3);
  const int nb   = swz % NBX;
  const int mb   = swz / NBX;
  const int brow = mb * 128;
  const int bcol = nb * TN;

  auto stageA = [&](int buf, int t, int j) {
    const int c   = j * 256 + tid;
    const int row = c >> 2, ch = c & 3;
    const ushort* src = A + (size_t)(brow + row) * K + t * 32 + ((ch ^ ((row >> 1) & 3)) << 3);
    __builtin_amdgcn_global_load_lds(GLOBAL_AS(src),
        LDS_AS(&sA[buf][(j * 256 + (w << 6)) << 3]), 16, 0, 0);
  };
  auto stageB = [&](int buf, int t, int j) {
    const int c   = j * 256 + tid;
    const int row = c >> 2, ch = c & 3;
    const ushort* src = Bt + (size_t)(bcol + row) * K + t * 32 + ((ch ^ ((row >> 1) & 3)) << 3);
    __builtin_amdgcn_global_load_lds(GLOBAL_AS(src),
        LDS_AS(&sB[buf][(j * 256 + (w << 6)) << 3]), 16, 0, 0);
  };
  auto ldA = [&](int buf, int mf) -> bf16x8 {
    const int row = (wr << 6) + (mf << 4) + lr;
    return *reinterpret_cast<const bf16x8*>(&sA[buf][(row << 5) + ((kq ^ ((row >> 1) & 3)) << 3)]);
  };
  auto ldB = [&](int buf, int nf) -> bf16x8 {
    const int row = (wc << 6) + (nf << 4) + lr;
    return *reinterpret_cast<const bf16x8*>(&sB[buf][(row << 5) + ((kq ^ ((row >> 1) & 3)) << 3)]);
  };

  f32x4 acc[4][4];
  #pragma unroll
  for (int mi = 0; mi < 4; ++mi)
    #pragma unroll
    for (int ni = 0; ni < 4; ++ni)
      acc[mi][ni] = (f32x4){0.f, 0.f, 0.f, 0.f};

  // ---- prologue: stage K-steps 0 and 1
  stageA(0, 0, 0); stageA(0, 0, 1); stageB(0, 0, 0); stageB(0, 0, 1);
  stageA(1, 1, 0); stageA(1, 1, 1); stageB(1, 1, 0); stageB(1, 1, 1);
  asm volatile("s_waitcnt vmcnt(4)" ::: "memory");
  SB0(); __builtin_amdgcn_s_barrier(); SB0();

  for (int t = 0; t < NT; ++t) {
    const int buf  = t % 3;
    const int nbuf = (t + 2) % 3;
    const bool more = (t + 2) < NT;

    bf16x8 af[4], bfr[4];
    #pragma unroll
    for (int mf = 0; mf < 4; ++mf) af[mf] = ldA(buf, mf);
    #pragma unroll
    for (int nf = 0; nf < 4; ++nf) bfr[nf] = ldB(buf, nf);
    if (more) { stageA(nbuf, t + 2, 0); stageA(nbuf, t + 2, 1);
                stageB(nbuf, t + 2, 0); stageB(nbuf, t + 2, 1); }
    SB0();
    __builtin_amdgcn_s_setprio(1);
    #pragma unroll
    for (int mi = 0; mi < 4; ++mi)
      #pragma unroll
      for (int ni = 0; ni < 4; ++ni)
        acc[mi][ni] = __builtin_amdgcn_mfma_f32_16x16x32_bf16(af[mi], bfr[ni], acc[mi][ni], 0, 0, 0);
    __builtin_amdgcn_s_setprio(0);
    SB0();
    if (more) asm volatile("s_waitcnt vmcnt(4)" ::: "memory");
    else      asm volatile("s_waitcnt vmcnt(0)" ::: "memory");
    SB0(); __builtin_amdgcn_s_barrier(); SB0();
  }

  // ---- epilogue: LDS-staged, coalesced 16-B stores (values bit-identical) ---
  if constexpr (MODE == 0) {
    ushort* sEp = (ushort*)&sA[0][0];             // 32 x 144 bf16 = 9 KB
    constexpr int ES = TN + 16;
    const int which = bcol >> 9;                  // tile-uniform tensor select
    ushort* dst = (which == 0) ? Cq : ((which == 1) ? Ck : Cv);
    const float* bsel = (which == 0) ? b0 : ((which == 1) ? b1 : b2);
    const int ncol0 = bcol & 511;
    #pragma unroll
    for (int mi = 0; mi < 4; ++mi) {
      if (mi) __syncthreads();
      #pragma unroll
      for (int nf = 0; nf < 4; ++nf) {
        const int col = wc * 64 + nf * 16 + lr;
        const float bb = bsel[ncol0 + col];
        #pragma unroll
        for (int r = 0; r < 4; ++r)
          sEp[(wr * 16 + kq * 4 + r) * ES + col] = f2bf(acc[mi][nf][r] + bb);
      }
      __syncthreads();
      #pragma unroll
      for (int it = 0; it < 2; ++it) {
        const int idx = tid + it * 256;           // 512 16-B chunks
        const int rr  = idx >> 4;
        const int cc  = (idx & 15) * 8;
        uint4 v = *reinterpret_cast<const uint4*>(&sEp[rr * ES + cc]);
        const int grow = brow + (rr >> 4) * 64 + mi * 16 + (rr & 15);
        *reinterpret_cast<uint4*>(&dst[(size_t)grow * DD + ncol0 + cc]) = v;
      }
    }
  } else {
    float* sEpF = (float*)&sA[0][0];              // 32 x 136 f32
    constexpr int ES = TN + 8;
    #pragma unroll
    for (int mi = 0; mi < 4; ++mi) {
      if (mi) __syncthreads();
      #pragma unroll
      for (int nf = 0; nf < 4; ++nf) {
        const int col = wc * 64 + nf * 16 + lr;
        const float bb = b0[bcol + col];
        #pragma unroll
        for (int r = 0; r < 4; ++r)
          sEpF[(wr * 16 + kq * 4 + r) * ES + col] = acc[mi][nf][r] + bb;
      }
      __syncthreads();
      #pragma unroll
      for (int it = 0; it < 4; ++it) {
        const int idx = tid + it * 256;           // 1024 16-B chunks
        const int rr  = idx >> 5;
        const int cc  = (idx & 31) * 4;
        float4 v = *reinterpret_cast<const float4*>(&sEpF[rr * ES + cc]);
        const int grow = brow + (rr >> 4) * 64 + mi * 16 + (rr & 15);
        *reinterpret_cast<float4*>(&Cf[(size_t)grow * N + bcol + cc]) = v;
      }
    }
  }
}

// ---------------- fused block-sum of K,V -> Khi/Klo/Vb (no atomics) ----------
__global__ __launch_bounds__(256) void sumkv_fused(
    const ushort* __restrict__ K, const ushort* __restrict__ V,
    ushort* __restrict__ Khi, ushort* __restrict__ Klo, ushort* __restrict__ Vb)
{
  __shared__ float kbuf[4][64][9];
  __shared__ float vbuf[4][64][9];
  const int bs   = blockIdx.x;          // b*64 + s
  const int b    = bs >> 6, s = bs & 63;
  const int lane = threadIdx.x & 63;
  const int kbq  = threadIdx.x >> 6;
  const size_t rowbase = ((size_t)b * LL + s) * DD + lane * 8;

  uint4 ku[16], vu[16];
  #pragma unroll
  for (int i = 0; i < 16; ++i) {
    const size_t off = rowbase + (size_t)(kbq * 16 + i) * BS * DD;
    ku[i] = *reinterpret_cast<const uint4*>(K + off);
    vu[i] = *reinterpret_cast<const uint4*>(V + off);
  }
  float ak[8] = {0,0,0,0,0,0,0,0}, av[8] = {0,0,0,0,0,0,0,0};
  #pragma unroll
  for (int i = 0; i < 16; ++i) {
    ak[0] += bflo(ku[i].x); ak[1] += bfhi(ku[i].x); ak[2] += bflo(ku[i].y); ak[3] += bfhi(ku[i].y);
    ak[4] += bflo(ku[i].z); ak[5] += bfhi(ku[i].z); ak[6] += bflo(ku[i].w); ak[7] += bfhi(ku[i].w);
    av[0] += bflo(vu[i].x); av[1] += bfhi(vu[i].x); av[2] += bflo(vu[i].y); av[3] += bfhi(vu[i].y);
    av[4] += bflo(vu[i].z); av[5] += bfhi(vu[i].z); av[6] += bflo(vu[i].w); av[7] += bfhi(vu[i].w);
  }
  #pragma unroll
  for (int j = 0; j < 8; ++j) { kbuf[kbq][lane][j] = ak[j]; vbuf[kbq][lane][j] = av[j]; }
  __syncthreads();

  const size_t wbase = (size_t)bs * DD + lane * 8;
  if (kbq == 0) {
    uint4 hi4, lo4;
    uint* hp = reinterpret_cast<uint*>(&hi4);
    uint* lp = reinterpret_cast<uint*>(&lo4);
    #pragma unroll
    for (int p = 0; p < 4; ++p) {
      uint hw = 0, lw = 0;
      #pragma unroll
      for (int q = 0; q < 2; ++q) {
        const int j = p * 2 + q;
        const float t = kbuf[0][lane][j] + kbuf[1][lane][j] +
                        kbuf[2][lane][j] + kbuf[3][lane][j];
        const ushort h = f2bf(t);
        const ushort l = f2bf(t - bf2f(h));
        hw |= (uint)h << (16 * q);
        lw |= (uint)l << (16 * q);
      }
      hp[p] = hw; lp[p] = lw;
    }
    *reinterpret_cast<uint4*>(Khi + wbase) = hi4;
    *reinterpret_cast<uint4*>(Klo + wbase) = lo4;
  } else if (kbq == 1) {
    uint4 o4;
    uint* op = reinterpret_cast<uint*>(&o4);
    #pragma unroll
    for (int p = 0; p < 4; ++p) {
      uint wv = 0;
      #pragma unroll
      for (int q = 0; q < 2; ++q) {
        const int j = p * 2 + q;
        const float t = vbuf[0][lane][j] + vbuf[1][lane][j] +
                        vbuf[2][lane][j] + vbuf[3][lane][j];
        wv |= (uint)f2bf(t) << (16 * q);
      }
      op[p] = wv;
    }
    *reinterpret_cast<uint4*>(Vb + wbase) = o4;
  }
}

// ---------------- MFMA two-pass block attention ------------------------------
// 24 KB LDS (sP aliased onto Klo buffer sCP) -> 6 blocks/CU; XCD-chunked grid.
__global__ __launch_bounds__(256) void attn_mfma(
    const ushort* __restrict__ Q, const ushort* __restrict__ Kg,
    const ushort* __restrict__ Vg, const ushort* __restrict__ Khi,
    const ushort* __restrict__ Klo, const ushort* __restrict__ Vsb,
    ushort* __restrict__ X)
{
  __shared__ __align__(16) ushort sA[64 * 64];   // K (pass1), Khi (pass2)
  __shared__ __align__(16) ushort sVt[64 * 64];  // V^T, then Vsum^T
  __shared__ __align__(16) ushort sCP[64 * 64];  // P (both passes) / Klo (pass2)
  const int bid = blockIdx.x;
  const int swz = (bid & 7) * 256 + (bid >> 3);  // XCD-chunked (2048 % 8 == 0)
  const int n = swz & 63, h = (swz >> 6) & 7, b = swz >> 9;
  const int tid  = threadIdx.x;
  const int lane = tid & 63;
  const int w    = tid >> 6;
  const int lr   = lane & 15, hi4 = lane >> 4;
  const float scale = 0.125f;

  const size_t tbase = ((size_t)(b * LL + n * BS)) * DD + h * HDIM;
  const size_t sbase = ((size_t)(b * BS)) * DD + h * HDIM;

  uint4 k1[2], v1[2], k2h[2], k2l[2], v2[2];
  int rr[2], cc[2];
  #pragma unroll
  for (int it = 0; it < 2; ++it) {
    const int i  = tid + it * 256;      // 0..511
    const int r  = i >> 3;
    const int c8 = (i & 7) << 3;
    rr[it] = r; cc[it] = c8;
    const size_t g1 = tbase + (size_t)r * DD + c8;
    const size_t g2 = sbase + (size_t)r * DD + c8;
    k1[it]  = *reinterpret_cast<const uint4*>(Kg  + g1);
    v1[it]  = *reinterpret_cast<const uint4*>(Vg  + g1);
    k2h[it] = *reinterpret_cast<const uint4*>(Khi + g2);
    k2l[it] = *reinterpret_cast<const uint4*>(Klo + g2);
    v2[it]  = *reinterpret_cast<const uint4*>(Vsb + g2);
  }
  bf16x8 qf[2];
  #pragma unroll
  for (int ks = 0; ks < 2; ++ks)
    qf[ks] = *reinterpret_cast<const bf16x8*>(
        Q + tbase + (size_t)(w * 16 + lr) * DD + ks * 32 + hi4 * 8);

  #pragma unroll
  for (int it = 0; it < 2; ++it) {
    *reinterpret_cast<uint4*>(&sA[swb(rr[it], cc[it] << 1)]) = k1[it];
    const uint u[4] = {v1[it].x, v1[it].y, v1[it].z, v1[it].w};
    #pragma unroll
    for (int j = 0; j < 4; ++j) {
      sVt[swb(cc[it] + 2 * j,     rr[it] << 1)] = (ushort)(u[j] & 0xffff);
      sVt[swb(cc[it] + 2 * j + 1, rr[it] << 1)] = (ushort)(u[j] >> 16);
    }
  }
  __syncthreads();

  f32x4 xacc[4];
  #pragma unroll
  for (int dt = 0; dt < 4; ++dt) xacc[dt] = (f32x4){0.f, 0.f, 0.f, 0.f};

  // ================= PASS 1 =================
  {
    f32x4 st[4];
    #pragma unroll
    for (int t = 0; t < 4; ++t) st[t] = (f32x4){0.f, 0.f, 0.f, 0.f};
    #pragma unroll
    for (int ks = 0; ks < 2; ++ks) {
      #pragma unroll
      for (int t = 0; t < 4; ++t) {
        bf16x8 kf = *reinterpret_cast<const bf16x8*>(
            &sA[swb(t * 16 + lr, (ks * 32 + hi4 * 8) << 1)]);
        st[t] = __builtin_amdgcn_mfma_f32_16x16x32_bf16(kf, qf[ks], st[t], 0, 0, 0);
      }
    }
    float e[4][4];
    float mx = -1e30f;
    #pragma unroll
    for (int t = 0; t < 4; ++t)
      #pragma unroll
      for (int r = 0; r < 4; ++r) { e[t][r] = st[t][r] * scale; mx = fmaxf(mx, e[t][r]); }
    mx = fmaxf(mx, __shfl_xor(mx, 16));
    mx = fmaxf(mx, __shfl_xor(mx, 32));
    float sum = 0.f;
    #pragma unroll
    for (int t = 0; t < 4; ++t)
      #pragma unroll
      for (int r = 0; r < 4; ++r) { e[t][r] = __expf(e[t][r] - mx); sum += e[t][r]; }
    sum += __shfl_xor(sum, 16);
    sum += __shfl_xor(sum, 32);
    const float inv = 1.0f / sum;
    #pragma unroll
    for (int t = 0; t < 4; ++t) {
      ushort4 p4;
      p4.x = f2bf(e[t][0] * inv); p4.y = f2bf(e[t][1] * inv);
      p4.z = f2bf(e[t][2] * inv); p4.w = f2bf(e[t][3] * inv);
      *reinterpret_cast<ushort4*>(&sCP[swb(w * 16 + lr, (t * 16 + hi4 * 4) << 1)]) = p4;
    }
    #pragma unroll
    for (int ks = 0; ks < 2; ++ks) {
      bf16x8 pa = *reinterpret_cast<const bf16x8*>(
          &sCP[swb(w * 16 + lr, (ks * 32 + hi4 * 8) << 1)]);
      #pragma unroll
      for (int dt = 0; dt < 4; ++dt) {
        bf16x8 vb = *reinterpret_cast<const bf16x8*>(
            &sVt[swb(dt * 16 + lr, (ks * 32 + hi4 * 8) << 1)]);
        xacc[dt] = __builtin_amdgcn_mfma_f32_16x16x32_bf16(pa, vb, xacc[dt], 0, 0, 0);
      }
    }
  }
  __syncthreads();

  #pragma unroll
  for (int it = 0; it < 2; ++it) {
    *reinterpret_cast<uint4*>(&sA[swb(rr[it], cc[it] << 1)])  = k2h[it];
    *reinterpret_cast<uint4*>(&sCP[swb(rr[it], cc[it] << 1)]) = k2l[it];
    const uint u[4] = {v2[it].x, v2[it].y, v2[it].z, v2[it].w};
    #pragma unroll
    for (int j = 0; j < 4; ++j) {
      sVt[swb(cc[it] + 2 * j,     rr[it] << 1)] = (ushort)(u[j] & 0xffff);
      sVt[swb(cc[it] + 2 * j + 1, rr[it] << 1)] = (ushort)(u[j] >> 16);
    }
  }
  __syncthreads();

  // ================= PASS 2 =================
  {
    f32x4 st[4];
    #pragma unroll
    for (int t = 0; t < 4; ++t) st[t] = (f32x4){0.f, 0.f, 0.f, 0.f};
    #pragma unroll
    for (int ks = 0; ks < 2; ++ks) {
      #pragma unroll
      for (int t = 0; t < 4; ++t) {
        bf16x8 kh = *reinterpret_cast<const bf16x8*>(
            &sA[swb(t * 16 + lr, (ks * 32 + hi4 * 8) << 1)]);
        st[t] = __builtin_amdgcn_mfma_f32_16x16x32_bf16(kh, qf[ks], st[t], 0, 0, 0);
        bf16x8 kl = *reinterpret_cast<const bf16x8*>(
            &sCP[swb(t * 16 + lr, (ks * 32 + hi4 * 8) << 1)]);
        st[t] = __builtin_amdgcn_mfma_f32_16x16x32_bf16(kl, qf[ks], st[t], 0, 0, 0);
      }
    }
    __syncthreads();   // all Klo reads done before P overwrites sCP
    float e[4][4];
    float mx = -1e30f;
    #pragma unroll
    for (int t = 0; t < 4; ++t)
      #pragma unroll
      for (int r = 0; r < 4; ++r) { e[t][r] = st[t][r] * scale; mx = fmaxf(mx, e[t][r]); }
    mx = fmaxf(mx, __shfl_xor(mx, 16));
    mx = fmaxf(mx, __shfl_xor(mx, 32));
    float sum = 0.f;
    #pragma unroll
    for (int t = 0; t < 4; ++t)
      #pragma unroll
      for (int r = 0; r < 4; ++r) { e[t][r] = __expf(e[t][r] - mx); sum += e[t][r]; }
    sum += __shfl_xor(sum, 16);
    sum += __shfl_xor(sum, 32);
    const float inv = 1.0f / sum;
    #pragma unroll
    for (int t = 0; t < 4; ++t) {
      ushort4 p4;
      p4.x = f2bf(e[t][0] * inv); p4.y = f2bf(e[t][1] * inv);
      p4.z = f2bf(e[t][2] * inv); p4.w = f2bf(e[t][3] * inv);
      *reinterpret_cast<ushort4*>(&sCP[swb(w * 16 + lr, (t * 16 + hi4 * 4) << 1)]) = p4;
    }
    #pragma unroll
    for (int ks = 0; ks < 2; ++ks) {
      bf16x8 pa = *reinterpret_cast<const bf16x8*>(
          &sCP[swb(w * 16 + lr, (ks * 32 + hi4 * 8) << 1)]);
      #pragma unroll
      for (int dt = 0; dt < 4; ++dt) {
        bf16x8 vb = *reinterpret_cast<const bf16x8*>(
            &sVt[swb(dt * 16 + lr, (ks * 32 + hi4 * 8) << 1)]);
        xacc[dt] = __builtin_amdgcn_mfma_f32_16x16x32_bf16(pa, vb, xacc[dt], 0, 0, 0);
      }
    }
  }

  #pragma unroll
  for (int dt = 0; dt < 4; ++dt)
    #pragma unroll
    for (int r = 0; r < 4; ++r)
      X[tbase + (size_t)(w * 16 + hi4 * 4 + r) * DD + dt * 16 + lr] = f2bf(xacc[dt][r]);
}

// ---------------- launcher ---------------------------------------------------
extern "C" void kernel_launch(void* const* d_in, const int* in_sizes, int n_in,
                              void* d_out, int out_size, void* d_ws, size_t ws_size,
                              hipStream_t stream) {
  const float* x_in = (const float*)d_in[0];
  const float* Wq   = (const float*)d_in[1];
  const float* bq   = (const float*)d_in[2];
  const float* Wk   = (const float*)d_in[3];
  const float* bk   = (const float*)d_in[4];
  const float* Wv   = (const float*)d_in[5];
  const float* bv   = (const float*)d_in[6];
  const float* Wout = (const float*)d_in[9];
  const float* bout = (const float*)d_in[10];
  float* out = (float*)d_out;

  const size_t NTOK = (size_t)MTOT * DD;          // 8,388,608 elems
  const size_t NSUM = (size_t)BB * BS * DD;       // 131072 elems
  char* ws = (char*)d_ws;
  ushort* xb      = (ushort*)ws;            ws += NTOK * 2;
  ushort* Qb      = (ushort*)ws;            ws += NTOK * 2;
  ushort* Kb      = (ushort*)ws;            ws += NTOK * 2;
  ushort* Vb      = (ushort*)ws;            ws += NTOK * 2;
  ushort* Xb      = (ushort*)ws;            ws += NTOK * 2;
  ushort* Wqkv_t  = (ushort*)ws;            ws += (size_t)1536 * 512 * 2;
  ushort* Wout_t  = (ushort*)ws;            ws += (size_t)512 * 512 * 2;
  ushort* KhiB    = (ushort*)ws;            ws += NSUM * 2;
  ushort* KloB    = (ushort*)ws;            ws += NSUM * 2;
  ushort* VsB     = (ushort*)ws;            ws += NSUM * 2;

  // fused prep: 8192 cast blocks + 1024 transpose blocks
  prep_fused<<<8192 + 1024, 256, 0, stream>>>(
      x_in, xb, Wq, Wk, Wv, Wout, Wqkv_t, Wout_t);

  // QKV: tile 128x128, grid 12*128 = 1536 (3 blocks/CU -> exactly 2 rounds)
  gemm_pipe3<0><<<12 * 128, 256, 0, stream>>>(
      xb, Wqkv_t, bq, bk, bv, Qb, Kb, Vb, nullptr, 1536, 12);

  sumkv_fused<<<BB * BS, 256, 0, stream>>>(Kb, Vb, KhiB, KloB, VsB);

  attn_mfma<<<BB * HH * NBLK, 256, 0, stream>>>(Qb, Kb, Vb, KhiB, KloB, VsB, Xb);

  // out: tile 128x128, grid 4*128 = 512 (fully resident at 3 blocks/CU)
  gemm_pipe3<1><<<4 * 128, 256, 0, stream>>>(
      Xb, Wout_t, bout, nullptr, nullptr, nullptr, nullptr, nullptr, out, 512, 4);
}